// Round 13
// baseline (209.527 us; speedup 1.0000x reference)
//
#include <hip/hip_runtime.h>
#include <stdint.h>

typedef __bf16 bf16;
typedef __bf16 bf16x4 __attribute__((ext_vector_type(4)));
typedef __bf16 bf16x8 __attribute__((ext_vector_type(8)));
typedef float f32x4 __attribute__((ext_vector_type(4)));

#define TSEQ 2048
#define NHEAD 16
#define HDIM 64
#define CDIM 1024

#define AS1(p) ((const __attribute__((address_space(1))) void*)(p))
#define AS3(p) ((__attribute__((address_space(3))) void*)(p))

#if __has_builtin(__builtin_amdgcn_exp2f)
#define EXP2(x) __builtin_amdgcn_exp2f(x)
#else
#define EXP2(x) exp2f(x)
#endif

// ---------------- fp32 -> bf16 cast of x, Wqkv, Wout in ONE launch -----------
__global__ __launch_bounds__(256) void cast3_bf16(const float* __restrict__ in1, int n1,
                                                  const float* __restrict__ in2, int n2,
                                                  const float* __restrict__ in3, int n3,
                                                  bf16* __restrict__ out1,
                                                  bf16* __restrict__ out2,
                                                  bf16* __restrict__ out3) {
  int i = (blockIdx.x * 256 + threadIdx.x) * 8;
  const float* src;
  bf16* dst;
  if (i < n1) {
    src = in1 + i; dst = out1 + i;
  } else if (i < n1 + n2) {
    src = in2 + (i - n1); dst = out2 + (i - n1);
  } else if (i < n1 + n2 + n3) {
    src = in3 + (i - n1 - n2); dst = out3 + (i - n1 - n2);
  } else {
    return;
  }
  float4 a = *(const float4*)src;
  float4 b = *(const float4*)(src + 4);
  bf16x8 r;
  r[0] = (bf16)a.x; r[1] = (bf16)a.y; r[2] = (bf16)a.z; r[3] = (bf16)a.w;
  r[4] = (bf16)b.x; r[5] = (bf16)b.y; r[6] = (bf16)b.z; r[7] = (bf16)b.w;
  *(bf16x8*)dst = r;
}

// ---------------- GEMM1 + fused RoPE + fused V-transpose (r8-verified) -------
__global__ __launch_bounds__(256) void gemm_qkv_rope(const bf16* __restrict__ A,
                                                     const bf16* __restrict__ B,
                                                     const float* __restrict__ cosb,
                                                     const float* __restrict__ sinb,
                                                     bf16* __restrict__ Qb,
                                                     bf16* __restrict__ Kb,
                                                     bf16* __restrict__ Vt) {
  constexpr int K = 1024;
  __shared__ bf16 smem[8704];
  const int t = threadIdx.x;
  const int w = t >> 6, l = t & 63, g = l >> 4, ln = l & 15;
  const int wm = (w >> 1) * 64, wn = (w & 1) * 64;
  const int m0 = blockIdx.x * 128, n0 = blockIdx.y * 128;
  const int r0 = t >> 2, kc0 = (t & 3) * 8;

  f32x4 acc[4][4] = {};

  for (int k0 = 0; k0 < K; k0 += 32) {
    __syncthreads();
    __builtin_amdgcn_global_load_lds(AS1(A + (size_t)(m0 + r0) * K + k0 + kc0),
                                     AS3(&smem[t * 8]), 16, 0, 0);
    __builtin_amdgcn_global_load_lds(AS1(A + (size_t)(m0 + r0 + 64) * K + k0 + kc0),
                                     AS3(&smem[(t + 256) * 8]), 16, 0, 0);
    __builtin_amdgcn_global_load_lds(AS1(B + (size_t)(n0 + r0) * K + k0 + kc0),
                                     AS3(&smem[4096 + t * 8]), 16, 0, 0);
    __builtin_amdgcn_global_load_lds(AS1(B + (size_t)(n0 + r0 + 64) * K + k0 + kc0),
                                     AS3(&smem[4096 + (t + 256) * 8]), 16, 0, 0);
    __syncthreads();
    bf16x8 af[4], bfr[4];
#pragma unroll
    for (int i = 0; i < 4; i++) {
      af[i] = *(const bf16x8*)&smem[(wm + i * 16 + ln) * 32 + g * 8];
      bfr[i] = *(const bf16x8*)&smem[4096 + (wn + i * 16 + ln) * 32 + g * 8];
    }
#pragma unroll
    for (int i = 0; i < 4; i++)
#pragma unroll
      for (int j = 0; j < 4; j++)
        acc[i][j] = __builtin_amdgcn_mfma_f32_16x16x32_bf16(af[i], bfr[j], acc[i][j], 0, 0, 0);
  }

  const int part = n0 >> 10;  // 0=Q, 1=K, 2=V (uniform per block)
  if (part < 2) {
    bf16* dst = part ? Kb : Qb;
    const float qs = part ? 1.0f : 0.18033688011112042f;  // 0.125*log2(e) into Q
#pragma unroll
    for (int i = 0; i < 4; i++)
#pragma unroll
      for (int j = 0; j < 2; j++) {  // acc[i][j] = x1, acc[i][j+2] = x2 (col+32)
        int nl = (n0 & 1023) + wn + j * 16 + ln;
        int h = nl >> 6, d = nl & 31;
#pragma unroll
        for (int r = 0; r < 4; r++) {
          int row = m0 + wm + i * 16 + g * 4 + r;
          int tok = row & (TSEQ - 1), bb = row >> 11;
          float c = cosb[tok * 32 + d], s = sinb[tok * 32 + d];
          float a1 = acc[i][j][r], a2 = acc[i][j + 2][r];
          size_t ob = ((size_t)(bb * NHEAD + h) * TSEQ + tok) * HDIM + d;
          dst[ob] = (bf16)((a1 * c - a2 * s) * qs);
          dst[ob + 32] = (bf16)((a2 * c + a1 * s) * qs);
        }
      }
  } else {
    // V: transpose this block's 128(t) x 128(n) tile -> Vt[b,h,d,t]
    const int bb = m0 >> 11;
    const int tbase = m0 & (TSEQ - 1);
    const int nbase = n0 - 2048;
#pragma unroll
    for (int pass = 0; pass < 2; pass++) {
      __syncthreads();
      if ((w >> 1) == pass) {
#pragma unroll
        for (int i = 0; i < 4; i++)
#pragma unroll
          for (int j = 0; j < 4; j++) {
            int lr = i * 16 + g * 4;
            int lc = wn + j * 16 + ln;
#pragma unroll
            for (int r = 0; r < 4; r++)
              smem[(lr + r) * 132 + lc] = (bf16)acc[i][j][r];
          }
      }
      __syncthreads();
      for (int c = t; c < 1024; c += 256) {
        int ch = c >> 3, tc = c & 7;
        bf16x8 o;
#pragma unroll
        for (int j2 = 0; j2 < 8; j2++) o[j2] = smem[(tc * 8 + j2) * 132 + ch];
        int n = nbase + ch;
        int h = n >> 6, d = n & 63;
        *(bf16x8*)(Vt + ((size_t)((bb * NHEAD + h) * HDIM + d)) * TSEQ +
                   tbase + pass * 64 + tc * 8) = o;
      }
    }
  }
}

// ---------------- GEMM (out-proj): 64x128 tile, 512 blocks (r8-verified) -----
__global__ __launch_bounds__(256) void gemm_out(const bf16* __restrict__ A,
                                                const bf16* __restrict__ B,
                                                float* __restrict__ C,
                                                int M, int N, int K) {
  __shared__ bf16 As[64 * 32];
  __shared__ bf16 Bs[128 * 32];
  const int t = threadIdx.x;
  const int w = t >> 6, l = t & 63, g = l >> 4, ln = l & 15;
  const int m0 = blockIdx.x * 64, n0 = blockIdx.y * 128;
  const int r0 = t >> 2, kc0 = (t & 3) * 8;

  f32x4 acc[4][2] = {};

  for (int k0 = 0; k0 < K; k0 += 32) {
    __syncthreads();
    __builtin_amdgcn_global_load_lds(AS1(A + (size_t)(m0 + r0) * K + k0 + kc0),
                                     AS3(&As[t * 8]), 16, 0, 0);
    __builtin_amdgcn_global_load_lds(AS1(B + (size_t)(n0 + r0) * K + k0 + kc0),
                                     AS3(&Bs[t * 8]), 16, 0, 0);
    __builtin_amdgcn_global_load_lds(AS1(B + (size_t)(n0 + r0 + 64) * K + k0 + kc0),
                                     AS3(&Bs[(t + 256) * 8]), 16, 0, 0);
    __syncthreads();
    bf16x8 af[4], bfr[2];
#pragma unroll
    for (int i = 0; i < 4; i++)
      af[i] = *(const bf16x8*)&As[(i * 16 + ln) * 32 + g * 8];
#pragma unroll
    for (int j = 0; j < 2; j++)
      bfr[j] = *(const bf16x8*)&Bs[(w * 32 + j * 16 + ln) * 32 + g * 8];
#pragma unroll
    for (int i = 0; i < 4; i++)
#pragma unroll
      for (int j = 0; j < 2; j++)
        acc[i][j] = __builtin_amdgcn_mfma_f32_16x16x32_bf16(af[i], bfr[j], acc[i][j], 0, 0, 0);
  }
#pragma unroll
  for (int i = 0; i < 4; i++)
#pragma unroll
    for (int j = 0; j < 2; j++) {
      int row = m0 + i * 16 + g * 4;
      int col = n0 + w * 32 + j * 16 + ln;
#pragma unroll
      for (int r = 0; r < 4; r++)
        C[(size_t)(row + r) * N + col] = acc[i][j][r];
    }
}

// ---------------- Flash attention: r8 paired grid + r12 LDS fixes ------------
// grid 512, 512 threads. bh = bid&31 (XCD-local), pr = bid>>5; paired q-tiles
// {pr, 31-pr} -> every block exactly 17 iterations, all resident at t=0 (the
// r12 LPT experiment showed pairing+residency beats slack by ~11 µs).
// Split-k parity groups; no-max exp2 softmax; register-prefetch staging;
// stride-68 tiles (conflicts -10x vs 72) + Ps/Mrg LDS union (52.7 KB).
__global__ __launch_bounds__(512) void attn_fwd(const bf16* __restrict__ Q,
                                                const bf16* __restrict__ K,
                                                const bf16* __restrict__ Vt,
                                                bf16* __restrict__ ctx) {
  __shared__ bf16 Ks[2][64 * 68];
  __shared__ bf16 VTs[2][64 * 68];
  __shared__ __align__(16) char psmrg[17408];  // Ps (8*16*68 bf16) U Mrg (4*64*16 f32)
  bf16(*Ps)[16 * 68] = reinterpret_cast<bf16(*)[16 * 68]>(psmrg);
  float(*Mrg)[64][16] = reinterpret_cast<float(*)[64][16]>(psmrg);
  __shared__ float lred[4][16];
  __shared__ float linv[4][16];

  const int t = threadIdx.x;
  const int gp = t >> 8;
  const int tl = t & 255;
  const int w = t >> 6;
  const int w2 = w & 3;
  const int l = t & 63, g = l >> 4, ln = l & 15;
  const int bid = blockIdx.x;
  const int bh = bid & 31, pr = bid >> 5;  // XCD-locality swizzle (32 % 8 == 0)
  const size_t base = (size_t)bh * TSEQ * HDIM;

  const int r0 = tl >> 3, r1 = r0 + 32, ch0 = (tl & 7) * 8;
  bf16x8 kr0, kr1, vr0, vr1;

  for (int half = 0; half < 2; half++) {
    const int qb = half ? (31 - pr) : pr;
    const int q0 = qb * 64;
    const int q_global = q0 + w2 * 16 + ln;
    bf16x8 bq[2];
    bq[0] = *(const bf16x8*)(Q + base + (size_t)q_global * HDIM + g * 8);
    bq[1] = *(const bf16x8*)(Q + base + (size_t)q_global * HDIM + 32 + g * 8);
    f32x4 acc[4] = {};
    float l_run = 0.f;
    const int nit = (qb >> 1) + 1;

    if (gp <= qb) {  // prefetch first tile of this half
      kr0 = *(const bf16x8*)(K + base + (size_t)(gp * 64 + r0) * HDIM + ch0);
      kr1 = *(const bf16x8*)(K + base + (size_t)(gp * 64 + r1) * HDIM + ch0);
      vr0 = *(const bf16x8*)(Vt + base + (size_t)r0 * TSEQ + gp * 64 + ch0);
      vr1 = *(const bf16x8*)(Vt + base + (size_t)r1 * TSEQ + gp * 64 + ch0);
    }

    for (int i = 0; i < nit; i++) {
      const int kt = 2 * i + gp;
      const bool active = (kt <= qb);
      __syncthreads();  // prev iter's LDS readers done
      if (active) {
        *(bf16x8*)&Ks[gp][r0 * 68 + ch0] = kr0;
        *(bf16x8*)&Ks[gp][r1 * 68 + ch0] = kr1;
        *(bf16x8*)&VTs[gp][r0 * 68 + ch0] = vr0;
        *(bf16x8*)&VTs[gp][r1 * 68 + ch0] = vr1;
      }
      __syncthreads();
      const int ktn = kt + 2;  // prefetch next tile (overlaps compute below)
      if (ktn <= qb) {
        kr0 = *(const bf16x8*)(K + base + (size_t)(ktn * 64 + r0) * HDIM + ch0);
        kr1 = *(const bf16x8*)(K + base + (size_t)(ktn * 64 + r1) * HDIM + ch0);
        vr0 = *(const bf16x8*)(Vt + base + (size_t)r0 * TSEQ + ktn * 64 + ch0);
        vr1 = *(const bf16x8*)(Vt + base + (size_t)r1 * TSEQ + ktn * 64 + ch0);
      }
      if (active) {
        // S^T[k][q] (exp2 domain; Q pre-scaled with 0.125*log2e)
        f32x4 st[4] = {};
#pragma unroll
        for (int step = 0; step < 2; step++)
#pragma unroll
          for (int mt = 0; mt < 4; mt++) {
            bf16x8 ak = *(const bf16x8*)&Ks[gp][(mt * 16 + ln) * 68 + step * 32 + g * 8];
            st[mt] = __builtin_amdgcn_mfma_f32_16x16x32_bf16(ak, bq[step], st[mt], 0, 0, 0);
          }
        float vals[16];
        if (kt == qb) {  // diagonal: causal mask (uniform branch)
#pragma unroll
          for (int mt = 0; mt < 4; mt++)
#pragma unroll
            for (int r = 0; r < 4; r++) {
              int kg = kt * 64 + mt * 16 + g * 4 + r;
              vals[mt * 4 + r] = (kg <= q_global) ? fminf(st[mt][r], 60.f) : -INFINITY;
            }
        } else {
#pragma unroll
          for (int mt = 0; mt < 4; mt++)
#pragma unroll
            for (int r = 0; r < 4; r++) vals[mt * 4 + r] = fminf(st[mt][r], 60.f);
        }
        float psum = 0.f;
#pragma unroll
        for (int i2 = 0; i2 < 16; i2++) {
          float p = EXP2(vals[i2]);
          vals[i2] = p;
          psum += p;
        }
        psum += __shfl_xor(psum, 16);
        psum += __shfl_xor(psum, 32);
        l_run += psum;
        // P^T (C-layout) -> Ps[q_local][k], 8B vector writes
#pragma unroll
        for (int mt = 0; mt < 4; mt++) {
          bf16x4 pk;
#pragma unroll
          for (int r = 0; r < 4; r++) pk[r] = (bf16)vals[mt * 4 + r];
          *(bf16x4*)&Ps[w][ln * 68 + mt * 16 + g * 4] = pk;
        }
        // O += P * V
#pragma unroll
        for (int step = 0; step < 2; step++) {
          bf16x8 ap = *(const bf16x8*)&Ps[w][ln * 68 + step * 32 + g * 8];
#pragma unroll
          for (int nt = 0; nt < 4; nt++) {
            bf16x8 bv = *(const bf16x8*)&VTs[gp][(nt * 16 + ln) * 68 + step * 32 + g * 8];
            acc[nt] = __builtin_amdgcn_mfma_f32_16x16x32_bf16(ap, bv, acc[nt], 0, 0, 0);
          }
        }
      }
    }
    // merge the two k-parity partials (pure sums; Ps dead -> Mrg reuses its LDS)
    __syncthreads();
    if (gp == 1) {
#pragma unroll
      for (int nt = 0; nt < 4; nt++) *(f32x4*)&Mrg[w2][l][nt * 4] = acc[nt];
      if (l < 16) lred[w2][ln] = l_run;
    }
    __syncthreads();
    if (gp == 0) {
#pragma unroll
      for (int nt = 0; nt < 4; nt++) acc[nt] += *(const f32x4*)&Mrg[w2][l][nt * 4];
      float ltot = l_run + lred[w2][ln];
      if (l < 16) linv[w2][ln] = 1.0f / ltot;
      float lrow[4];
#pragma unroll
      for (int r = 0; r < 4; r++) lrow[r] = linv[w2][g * 4 + r];
      const int b = bh >> 4, h = bh & (NHEAD - 1);
#pragma unroll
      for (int nt = 0; nt < 4; nt++)
#pragma unroll
        for (int r = 0; r < 4; r++) {
          int q = q0 + w2 * 16 + g * 4 + r;
          ctx[(size_t)(b * TSEQ + q) * CDIM + h * HDIM + nt * 16 + ln] =
              (bf16)(acc[nt][r] * lrow[r]);
        }
    }
  }
}

extern "C" void kernel_launch(void* const* d_in, const int* in_sizes, int n_in,
                              void* d_out, int out_size, void* d_ws, size_t ws_size,
                              hipStream_t stream) {
  const float* x = (const float*)d_in[0];
  const float* cosb = (const float*)d_in[1];
  const float* sinb = (const float*)d_in[2];
  // d_in[3] = mask (bool) — unused; causality derived from indices
  const float* Wqkv = (const float*)d_in[4];
  const float* Wout = (const float*)d_in[5];
  float* out = (float*)d_out;

  // ws layout (42 MB):
  //  [0,8M)    x_bf -> ctx    [8M,14M) Wqkv_bf    [14M,16M) Wout_bf
  //  [16M,24M) Qb   [24M,32M) Kb   [32M,40M) Vt
  char* ws = (char*)d_ws;
  bf16* x_bf = (bf16*)ws;
  bf16* ctx = (bf16*)ws;
  bf16* Wqkv_bf = (bf16*)(ws + 8388608);
  bf16* Wout_bf = (bf16*)(ws + 14680064);
  bf16* Qb = (bf16*)(ws + 16777216);
  bf16* Kb = (bf16*)(ws + 25165824);
  bf16* Vt = (bf16*)(ws + 33554432);

  cast3_bf16<<<(4194304 + 3145728 + 1048576) / 8 / 256, 256, 0, stream>>>(
      x, 4194304, Wqkv, 3145728, Wout, 1048576, x_bf, Wqkv_bf, Wout_bf);
  gemm_qkv_rope<<<dim3(32, 24), 256, 0, stream>>>(x_bf, Wqkv_bf, cosb, sinb, Qb, Kb, Vt);
  attn_fwd<<<512, 512, 0, stream>>>(Qb, Kb, Vt, ctx);
  gemm_out<<<dim3(64, 8), 256, 0, stream>>>(ctx, Wout_bf, out, 4096, 1024, 1024);
}